// Round 6
// baseline (409.014 us; speedup 1.0000x reference)
//
#include <hip/hip_runtime.h>
#include <hip/hip_bf16.h>
#include <math.h>

typedef unsigned int uint;
typedef unsigned short ushort;
typedef __attribute__((ext_vector_type(8))) short short8;   // 8 bf16 = 4 VGPRs
typedef __attribute__((ext_vector_type(4))) float f32x4;    // MFMA accumulator

__device__ __forceinline__ float bf_lo(uint u) { return __uint_as_float(u << 16); }
__device__ __forceinline__ float bf_hi(uint u) { return __uint_as_float(u & 0xffff0000u); }
__device__ __forceinline__ ushort f2bf(float f) {
  __hip_bfloat16 h = __float2bfloat16(f);   // RNE
  return *reinterpret_cast<ushort*>(&h);
}
__device__ __forceinline__ uint pack2(float a, float b) {
  return (uint)f2bf(a) | ((uint)f2bf(b) << 16);
}

// ===================== CSR build (XCD-partitioned count/fill) =====================
__global__ __launch_bounds__(256) void k_count(
    const int* __restrict__ edges, int* __restrict__ cnt, int E, int npp, int nbp) {
  int part = blockIdx.x & 7;
  int lo = part * npp, hi = lo + npp;
  for (int e = (int)(blockIdx.x >> 3) * 256 + threadIdx.x; e < E; e += nbp * 256) {
    int d = edges[E + e];
    if (d >= lo && d < hi) atomicAdd(&cnt[d], 1);
  }
}

// scan1 also emits dinv = rsqrt(deg+1) (fused former k_dinv)
__global__ void k_scan1(const int* __restrict__ cnt, int* __restrict__ incl,
                        int* __restrict__ bsum, float* __restrict__ dinv, int n) {
  __shared__ int s[256];
  int tid = threadIdx.x;
  int gid = blockIdx.x * 256 + tid;
  int x = (gid < n) ? cnt[gid] : 0;
  if (gid < n) dinv[gid] = rsqrtf((float)x + 1.0f);
  s[tid] = x;
  __syncthreads();
  #pragma unroll
  for (int off = 1; off < 256; off <<= 1) {
    int t = (tid >= off) ? s[tid - off] : 0;
    __syncthreads();
    x += t; s[tid] = x;
    __syncthreads();
  }
  incl[gid] = x;
  if (tid == 255) bsum[blockIdx.x] = x;
}

__global__ void k_scan2(int* __restrict__ bsum, int nb) {
  __shared__ int s[256];
  int tid = threadIdx.x;
  int x = (tid < nb) ? bsum[tid] : 0;
  s[tid] = x;
  __syncthreads();
  #pragma unroll
  for (int off = 1; off < 256; off <<= 1) {
    int t = (tid >= off) ? s[tid - off] : 0;
    __syncthreads();
    x += t; s[tid] = x;
    __syncthreads();
  }
  if (tid < nb) bsum[tid] = x;
}

__global__ void k_scan3(const int* __restrict__ incl, const int* __restrict__ cnt,
                        const int* __restrict__ bsum, int* __restrict__ offs,
                        int* __restrict__ curs, int n, int E) {
  int gid = blockIdx.x * 256 + threadIdx.x;
  if (gid < n) {
    int base = (blockIdx.x > 0) ? bsum[blockIdx.x - 1] : 0;
    int v = incl[gid] - cnt[gid] + base;   // exclusive
    offs[gid] = v;
    curs[gid] = v;
  }
  if (gid == 0) offs[n] = E;
}

__global__ __launch_bounds__(256) void k_fill(
    const int* __restrict__ edges, int* __restrict__ curs,
    int* __restrict__ csr, int E, int npp, int nbp) {
  int part = blockIdx.x & 7;
  int lo = part * npp, hi = lo + npp;
  for (int e = (int)(blockIdx.x >> 3) * 256 + threadIdx.x; e < E; e += nbp * 256) {
    int d = edges[E + e];
    if (d >= lo && d < hi) {
      int s = edges[e];
      int pos = atomicAdd(&curs[d], 1);
      csr[pos] = s;
    }
  }
}

// ===================== W prep: fp32 [k][c] -> bf16 Wt [col][k] =====================
__global__ void k_prepw(const float* __restrict__ W_in, const float* __restrict__ W1,
                        const float* __restrict__ W2, ushort* __restrict__ Wt) {
  int b = blockIdx.x;
  const float* W = (b < 8) ? W_in : (b < 16) ? W1 : W2;
  ushort* dst = Wt + (size_t)(b >> 3) * 16384;
  int id = (b & 7) * 256 + threadIdx.x;    // 0..2047
  int col = id >> 4, kc = id & 15;
  const float* src = W + (size_t)(kc * 8) * 128 + col;
  uint4 pk;
  pk.x = pack2(src[0],       src[128]);
  pk.y = pack2(src[2 * 128], src[3 * 128]);
  pk.z = pack2(src[4 * 128], src[5 * 128]);
  pk.w = pack2(src[6 * 128], src[7 * 128]);
  ((uint4*)dst)[id] = pk;
}

// ===================== x prep: xs = bf16(dinv[row] * x) =====================
__global__ void k_xconv(const float* __restrict__ x, const float* __restrict__ dinv,
                        ushort* __restrict__ xs, int n) {
  int i = blockIdx.x * 256 + threadIdx.x;   // one per 4 floats
  if (i < n * 32) {
    float d = dinv[i >> 5];
    float4 v = ((const float4*)x)[i];
    uint2 o;
    o.x = pack2(v.x * d, v.y * d);
    o.y = pack2(v.z * d, v.w * d);
    ((uint2*)xs)[i] = o;
  }
}

// ===================== fused layer: Hout = act( agg(Hin) @ W + b ) =====================
// Hin rows are PRE-SCALED: Hs = dinv .* H, so Z_u = Hs_u + dinv_u * sum Hs_s.
// Block = 256 thr (4 waves) = 64 rows. Phase 1: each wave aggregates its 16 rows
// into swizzled LDS (bf16). Phase 2: MFMA vs W (LDS, swizzled), bias/relu epilogue,
// optional dinv pre-scale of the output for the next layer's gather.
template <int RELU, int SCALE_OUT>
__global__ __launch_bounds__(256) void k_layer(
    const ushort* __restrict__ Hin, const ushort* __restrict__ Wt,
    const int* __restrict__ offs, const int* __restrict__ csr,
    const float* __restrict__ dinv, const float* __restrict__ bias,
    ushort* __restrict__ Hout, int n)
{
  __shared__ ushort sW[128 * 128];   // 32 KB, chunk (col,kc^(col&7))
  __shared__ ushort sZ[64 * 128];    // 16 KB, chunk (row,kc^(row&7))
  int tid = threadIdx.x;
  {
    const uint4* Wt4 = (const uint4*)Wt;
    uint4* sW4 = (uint4*)sW;
    #pragma unroll
    for (int j = 0; j < 8; ++j) {
      int id = j * 256 + tid;
      int col = id >> 4, kc = id & 15;
      sW4[(col << 4) | (kc ^ (col & 7))] = Wt4[id];
    }
  }

  int wid = tid >> 6, lane = tid & 63;
  int rbase = blockIdx.x * 64;
  const uint* Hu = (const uint*)Hin;
  uint* sZw = (uint*)sZ;
  int kcw = lane >> 2, wd = lane & 3;   // chunk / word within chunk for sZ store

  for (int rr = 0; rr < 16; ++rr) {
    int rl = (wid << 4) + rr;
    int u = rbase + rl;
    float zx = 0.f, zy = 0.f;
    if (u < n) {
      uint su = Hu[(size_t)u * 64 + lane];   // self term = Hs_u
      int e0 = offs[u], e1 = offs[u + 1];
      float ax = 0.f, ay = 0.f;
      int e = e0;
      for (; e + 8 <= e1; e += 8) {
        int s0 = csr[e],     s1 = csr[e + 1], s2 = csr[e + 2], s3 = csr[e + 3];
        int s4 = csr[e + 4], s5 = csr[e + 5], s6 = csr[e + 6], s7 = csr[e + 7];
        uint v0 = Hu[(size_t)s0 * 64 + lane];
        uint v1 = Hu[(size_t)s1 * 64 + lane];
        uint v2 = Hu[(size_t)s2 * 64 + lane];
        uint v3 = Hu[(size_t)s3 * 64 + lane];
        uint v4 = Hu[(size_t)s4 * 64 + lane];
        uint v5 = Hu[(size_t)s5 * 64 + lane];
        uint v6 = Hu[(size_t)s6 * 64 + lane];
        uint v7 = Hu[(size_t)s7 * 64 + lane];
        ax += ((bf_lo(v0) + bf_lo(v1)) + (bf_lo(v2) + bf_lo(v3))) +
              ((bf_lo(v4) + bf_lo(v5)) + (bf_lo(v6) + bf_lo(v7)));
        ay += ((bf_hi(v0) + bf_hi(v1)) + (bf_hi(v2) + bf_hi(v3))) +
              ((bf_hi(v4) + bf_hi(v5)) + (bf_hi(v6) + bf_hi(v7)));
      }
      for (; e + 2 <= e1; e += 2) {
        int s0 = csr[e], s1 = csr[e + 1];
        uint v0 = Hu[(size_t)s0 * 64 + lane];
        uint v1 = Hu[(size_t)s1 * 64 + lane];
        ax += bf_lo(v0) + bf_lo(v1);
        ay += bf_hi(v0) + bf_hi(v1);
      }
      if (e < e1) {
        uint v = Hu[(size_t)csr[e] * 64 + lane];
        ax += bf_lo(v); ay += bf_hi(v);
      }
      float du = dinv[u];
      zx = fmaf(ax, du, bf_lo(su));
      zy = fmaf(ay, du, bf_hi(su));
    }
    sZw[(rl << 6) | (((kcw ^ (rl & 7)) << 2) | wd)] = pack2(zx, zy);
  }
  __syncthreads();

  int lr = lane & 15, lg = lane >> 4;
  f32x4 acc[8];
  #pragma unroll
  for (int cf = 0; cf < 8; ++cf) acc[cf] = (f32x4){0.f, 0.f, 0.f, 0.f};

  int rl2 = (wid << 4) + lr;
  #pragma unroll
  for (int ks = 0; ks < 4; ++ks) {
    int kc = (ks << 2) | lg;
    short8 a = *((const short8*)sZ + ((rl2 << 4) | (kc ^ (rl2 & 7))));
    #pragma unroll
    for (int cf = 0; cf < 8; ++cf) {
      int col = (cf << 4) | lr;
      const short8* bp = (const short8*)sW + ((col << 4) | (kc ^ (lr & 7)));
      acc[cf] = __builtin_amdgcn_mfma_f32_16x16x32_bf16(a, *bp, acc[cf], 0, 0, 0);
    }
  }

  float bj[8];
  #pragma unroll
  for (int cf = 0; cf < 8; ++cf) bj[cf] = bias[(cf << 4) | lr];

  #pragma unroll
  for (int v = 0; v < 4; ++v) {
    int row = rbase + (wid << 4) + (lg << 2) + v;
    if (row < n) {
      float s = SCALE_OUT ? dinv[row] : 1.f;
      ushort* dst = Hout + (size_t)row * 128 + lr;
      #pragma unroll
      for (int cf = 0; cf < 8; ++cf) {
        float val = acc[cf][v] + bj[cf];
        if (RELU) val = fmaxf(val, 0.f);
        dst[cf << 4] = f2bf(val * s);
      }
    }
  }
}

// ===================== head: logits + fused log_softmax (bf16 H) =====================
__global__ __launch_bounds__(256) void k_head(
    const ushort* __restrict__ H, const float* __restrict__ Wo,
    const float* __restrict__ bo, float* __restrict__ out, int n)
{
  __shared__ float sWo[128 * 40];   // 20 KB
  __shared__ float sX[128 * 64];    // 32 KB, swizzled transpose
  int tid = threadIdx.x;
  int rbase = blockIdx.x * 64;

  {
    const float4* Wo4 = (const float4*)Wo;
    float4* sWo4 = (float4*)sWo;
    #pragma unroll
    for (int i = 0; i < 5; ++i) sWo4[i * 256 + tid] = Wo4[i * 256 + tid];
  }
  {
    const uint4* H4 = (const uint4*)H;
    #pragma unroll
    for (int j = 0; j < 4; ++j) {
      int id = j * 256 + tid;
      int r = id & 63, kc8 = id >> 6;   // kc8 = 0..15, 8 k-elems each
      int row = rbase + r;
      uint4 v = make_uint4(0u, 0u, 0u, 0u);
      if (row < n) v = H4[(size_t)row * 16 + kc8];
      float f[8] = {bf_lo(v.x), bf_hi(v.x), bf_lo(v.y), bf_hi(v.y),
                    bf_lo(v.z), bf_hi(v.z), bf_lo(v.w), bf_hi(v.w)};
      #pragma unroll
      for (int j2 = 0; j2 < 8; ++j2) {
        int k = kc8 * 8 + j2;
        int swz = ((k >> 2) & 7) << 2;
        sX[k * 64 + (r ^ swz)] = f[j2];
      }
    }
  }
  __syncthreads();

  int cg = tid & 7;    // 8 col groups x 5 cols
  int rg = tid >> 3;   // 32 row groups x 2 rows
  float bj[5];
  #pragma unroll
  for (int j = 0; j < 5; ++j) bj[j] = bo[cg * 5 + j];
  float acc[2][5];
  #pragma unroll
  for (int i = 0; i < 2; ++i)
    #pragma unroll
    for (int j = 0; j < 5; ++j) acc[i][j] = bj[j];

  #pragma unroll 4
  for (int k = 0; k < 128; ++k) {
    int swz = ((k >> 2) & 7) << 2;
    float2 xv = *(const float2*)(sX + k * 64 + ((rg << 1) ^ swz));
    const float* wr = sWo + k * 40 + cg * 5;
    float w0 = wr[0], w1 = wr[1], w2 = wr[2], w3 = wr[3], w4 = wr[4];
    acc[0][0] = fmaf(xv.x, w0, acc[0][0]);
    acc[0][1] = fmaf(xv.x, w1, acc[0][1]);
    acc[0][2] = fmaf(xv.x, w2, acc[0][2]);
    acc[0][3] = fmaf(xv.x, w3, acc[0][3]);
    acc[0][4] = fmaf(xv.x, w4, acc[0][4]);
    acc[1][0] = fmaf(xv.y, w0, acc[1][0]);
    acc[1][1] = fmaf(xv.y, w1, acc[1][1]);
    acc[1][2] = fmaf(xv.y, w2, acc[1][2]);
    acc[1][3] = fmaf(xv.y, w3, acc[1][3]);
    acc[1][4] = fmaf(xv.y, w4, acc[1][4]);
  }

  #pragma unroll
  for (int i = 0; i < 2; ++i) {
    int row = rbase + (rg << 1) + i;
    float m = acc[i][0];
    m = fmaxf(m, acc[i][1]); m = fmaxf(m, acc[i][2]);
    m = fmaxf(m, acc[i][3]); m = fmaxf(m, acc[i][4]);
    m = fmaxf(m, __shfl_xor(m, 1));
    m = fmaxf(m, __shfl_xor(m, 2));
    m = fmaxf(m, __shfl_xor(m, 4));
    float s = 0.f;
    #pragma unroll
    for (int j = 0; j < 5; ++j) s += __expf(acc[i][j] - m);
    s += __shfl_xor(s, 1);
    s += __shfl_xor(s, 2);
    s += __shfl_xor(s, 4);
    float ls = m + __logf(s);
    if (row < n) {
      float* dst = out + (size_t)row * 40 + cg * 5;
      #pragma unroll
      for (int j = 0; j < 5; ++j) dst[j] = acc[i][j] - ls;
    }
  }
}

// ===================== launch =====================
extern "C" void kernel_launch(void* const* d_in, const int* in_sizes, int n_in,
                              void* d_out, int out_size, void* d_ws, size_t ws_size,
                              hipStream_t stream) {
  const float* x    = (const float*)d_in[0];
  const int*   edges= (const int*)d_in[1];
  const float* W_in = (const float*)d_in[2];
  const float* b_in = (const float*)d_in[3];
  const float* W1   = (const float*)d_in[4];
  const float* b1   = (const float*)d_in[5];
  const float* W2   = (const float*)d_in[6];
  const float* b2   = (const float*)d_in[7];
  const float* Wo   = (const float*)d_in[8];
  const float* bo   = (const float*)d_in[9];
  float* out = (float*)d_out;

  int N = in_sizes[0] / 128;
  int E = in_sizes[1] / 2;
  int NB = (N + 255) / 256;

  char* p = (char*)d_ws;
  auto alloc = [&](size_t bytes) {
    char* r = p; p += (bytes + 255) & ~(size_t)255; return r;
  };
  ushort* bufA = (ushort*)alloc((size_t)N * 128 * 2);
  ushort* bufB = (ushort*)alloc((size_t)N * 128 * 2);
  ushort* wt   = (ushort*)alloc(3 * 16384 * 2);
  int*   cnt  = (int*)  alloc((size_t)N * 4);
  float* dinv = (float*)alloc((size_t)N * 4);
  int*   incl = (int*)  alloc((size_t)NB * 256 * 4);
  int*   bsum = (int*)  alloc(256 * 4);
  int*   offs = (int*)  alloc((size_t)(N + 1) * 4);
  int*   curs = (int*)  alloc((size_t)N * 4);
  int*   csr  = (int*)  alloc((size_t)E * 4);
  (void)ws_size; (void)n_in; (void)out_size;

  // --- prep + CSR build ---
  int NPP = (N + 7) / 8;       // nodes per partition
  int NBP = 512;               // blocks per partition
  k_prepw<<<24, 256, 0, stream>>>(W_in, W1, W2, wt);
  hipMemsetAsync(cnt, 0, (size_t)N * 4, stream);
  k_count<<<NBP * 8, 256, 0, stream>>>(edges, cnt, E, NPP, NBP);
  k_scan1<<<NB, 256, 0, stream>>>(cnt, incl, bsum, dinv, N);
  k_scan2<<<1, 256, 0, stream>>>(bsum, NB);
  k_scan3<<<NB, 256, 0, stream>>>(incl, cnt, bsum, offs, curs, N, E);
  k_fill <<<NBP * 8, 256, 0, stream>>>(edges, curs, csr, E, NPP, NBP);

  // xs = bf16(dinv .* x)  -> bufA
  k_xconv<<<(N * 32 + 255) / 256, 256, 0, stream>>>(x, dinv, bufA, N);

  int GB = (N + 63) / 64;
  // layer 1: Hs1 = dinv .* (agg(x) @ W_in + b_in)          (no relu)
  k_layer<0, 1><<<GB, 256, 0, stream>>>(bufA, wt,             offs, csr, dinv, b_in, bufB, N);
  // layer 2: Hs2 = dinv .* relu(agg(H1) @ W1 + b1)
  k_layer<1, 1><<<GB, 256, 0, stream>>>(bufB, wt + 16384,     offs, csr, dinv, b1, bufA, N);
  // layer 3: H3 = relu(agg(H2) @ W2 + b2)                  (unscaled, feeds head)
  k_layer<1, 0><<<GB, 256, 0, stream>>>(bufA, wt + 2 * 16384, offs, csr, dinv, b2, bufB, N);

  // head + log_softmax (fused)
  k_head<<<GB, 256, 0, stream>>>(bufB, Wo, bo, out, N);
}

// Round 7
// 244.746 us; speedup vs baseline: 1.6712x; 1.6712x over previous
//
#include <hip/hip_runtime.h>
#include <hip/hip_bf16.h>
#include <math.h>

typedef unsigned int uint;
typedef unsigned short ushort;
typedef __attribute__((ext_vector_type(8))) short short8;   // 8 bf16 = 4 VGPRs
typedef __attribute__((ext_vector_type(4))) float f32x4;    // MFMA accumulator

__device__ __forceinline__ float bf_lo(uint u) { return __uint_as_float(u << 16); }
__device__ __forceinline__ float bf_hi(uint u) { return __uint_as_float(u & 0xffff0000u); }
__device__ __forceinline__ ushort f2bf(float f) {
  __hip_bfloat16 h = __float2bfloat16(f);   // RNE
  return *reinterpret_cast<ushort*>(&h);
}
__device__ __forceinline__ uint pack2(float a, float b) {
  return (uint)f2bf(a) | ((uint)f2bf(b) << 16);
}

// ===================== CSR build =====================
// count: single edge pass; 8 replicated count arrays, replica = blockIdx&7
// (round-robins onto XCDs) -> atomics stay XCD-local, edges read once.
__global__ __launch_bounds__(256) void k_count8(
    const int* __restrict__ edges, int* __restrict__ cnt8, int E, int n) {
  int* my = cnt8 + (size_t)(blockIdx.x & 7) * n;
  int stride = gridDim.x * 256;
  for (int e = blockIdx.x * 256 + threadIdx.x; e < E; e += stride)
    atomicAdd(&my[edges[E + e]], 1);
}

__global__ void k_cntred(const int* __restrict__ cnt8, int* __restrict__ cnt,
                         float* __restrict__ dinv, int n) {
  int i = blockIdx.x * 256 + threadIdx.x;
  if (i < n) {
    int s = 0;
    #pragma unroll
    for (int p = 0; p < 8; ++p) s += cnt8[(size_t)p * n + i];
    cnt[i] = s;
    dinv[i] = rsqrtf((float)s + 1.0f);   // +1 = self loop
  }
}

__global__ void k_scan1(const int* __restrict__ cnt, int* __restrict__ incl,
                        int* __restrict__ bsum, int n) {
  __shared__ int s[256];
  int tid = threadIdx.x;
  int gid = blockIdx.x * 256 + tid;
  int x = (gid < n) ? cnt[gid] : 0;
  s[tid] = x;
  __syncthreads();
  #pragma unroll
  for (int off = 1; off < 256; off <<= 1) {
    int t = (tid >= off) ? s[tid - off] : 0;
    __syncthreads();
    x += t; s[tid] = x;
    __syncthreads();
  }
  incl[gid] = x;
  if (tid == 255) bsum[blockIdx.x] = x;
}

__global__ void k_scan2(int* __restrict__ bsum, int nb) {
  __shared__ int s[256];
  int tid = threadIdx.x;
  int x = (tid < nb) ? bsum[tid] : 0;
  s[tid] = x;
  __syncthreads();
  #pragma unroll
  for (int off = 1; off < 256; off <<= 1) {
    int t = (tid >= off) ? s[tid - off] : 0;
    __syncthreads();
    x += t; s[tid] = x;
    __syncthreads();
  }
  if (tid < nb) bsum[tid] = x;
}

__global__ void k_scan3(const int* __restrict__ incl, const int* __restrict__ cnt,
                        const int* __restrict__ bsum, int* __restrict__ offs,
                        int* __restrict__ curs, int n, int E) {
  int gid = blockIdx.x * 256 + threadIdx.x;
  if (gid < n) {
    int base = (blockIdx.x > 0) ? bsum[blockIdx.x - 1] : 0;
    int v = incl[gid] - cnt[gid] + base;   // exclusive
    offs[gid] = v;
    curs[gid] = v;
  }
  if (gid == 0) offs[n] = E;
}

// fill: XCD-partitioned by dst range so curs atomics + csr line fills are L2-local.
__global__ __launch_bounds__(256) void k_fill(
    const int* __restrict__ edges, int* __restrict__ curs,
    int* __restrict__ csr, int E, int npp, int nbp) {
  int part = blockIdx.x & 7;
  int lo = part * npp, hi = lo + npp;
  for (int e = (int)(blockIdx.x >> 3) * 256 + threadIdx.x; e < E; e += nbp * 256) {
    int d = edges[E + e];
    if (d >= lo && d < hi) {
      int s = edges[e];
      int pos = atomicAdd(&curs[d], 1);
      csr[pos] = s;
    }
  }
}

// ===================== W prep: fp32 [k][c] -> bf16 Wt [col][k] =====================
__global__ void k_prepw(const float* __restrict__ W_in, const float* __restrict__ W1,
                        const float* __restrict__ W2, ushort* __restrict__ Wt) {
  int b = blockIdx.x;
  const float* W = (b < 8) ? W_in : (b < 16) ? W1 : W2;
  ushort* dst = Wt + (size_t)(b >> 3) * 16384;
  int id = (b & 7) * 256 + threadIdx.x;    // 0..2047
  int col = id >> 4, kc = id & 15;
  const float* src = W + (size_t)(kc * 8) * 128 + col;
  uint4 pk;
  pk.x = pack2(src[0],       src[128]);
  pk.y = pack2(src[2 * 128], src[3 * 128]);
  pk.z = pack2(src[4 * 128], src[5 * 128]);
  pk.w = pack2(src[6 * 128], src[7 * 128]);
  ((uint4*)dst)[id] = pk;
}

// ===================== MFMA GEMM: T = bf16( (A @ W) * dinv[row] ) =====================
// Block 256 thr = 4 waves; wave = 16 rows x 128 cols via 8x mfma_f32_16x16x32_bf16.
// W (bf16, pre-transposed [col][k]) in LDS with kc^(col&7) swizzle; A global->VGPR.
template <bool AF32>
__global__ __launch_bounds__(256) void k_gemm(
    const void* __restrict__ Ap, const ushort* __restrict__ Wt,
    const float* __restrict__ dinv, ushort* __restrict__ T, int n)
{
  __shared__ ushort sW[128 * 128];   // 32 KB: chunk (col,kc') at col*16+kc'
  int tid = threadIdx.x;
  {
    const uint4* Wt4 = (const uint4*)Wt;
    uint4* sW4 = (uint4*)sW;
    #pragma unroll
    for (int j = 0; j < 8; ++j) {
      int id = j * 256 + tid;
      int col = id >> 4, kc = id & 15;
      sW4[(col << 4) | (kc ^ (col & 7))] = Wt4[id];
    }
  }
  __syncthreads();

  int wid = tid >> 6, lane = tid & 63;
  int lr = lane & 15;    // A-row / B-col / D-col within fragment
  int lg = lane >> 4;    // k-group
  int rbase = blockIdx.x * 64 + wid * 16;
  int arow = rbase + lr;
  bool valid = arow < n;

  f32x4 acc[8];
  #pragma unroll
  for (int cf = 0; cf < 8; ++cf) acc[cf] = (f32x4){0.f, 0.f, 0.f, 0.f};

  #pragma unroll
  for (int ks = 0; ks < 4; ++ks) {
    short8 a = {};
    if (valid) {
      if constexpr (AF32) {
        const float4* Af = (const float4*)((const float*)Ap + (size_t)arow * 128) + (ks * 4 + lg) * 2;
        float4 u = Af[0], w = Af[1];
        union { uint4 u4; short8 s8; } cv;
        cv.u4.x = pack2(u.x, u.y); cv.u4.y = pack2(u.z, u.w);
        cv.u4.z = pack2(w.x, w.y); cv.u4.w = pack2(w.z, w.w);
        a = cv.s8;
      } else {
        a = ((const short8*)((const ushort*)Ap + (size_t)arow * 128))[ks * 4 + lg];
      }
    }
    int kc = (ks << 2) | lg;
    #pragma unroll
    for (int cf = 0; cf < 8; ++cf) {
      int col = (cf << 4) | lr;
      const short8* bp = (const short8*)sW + ((col << 4) | (kc ^ (lr & 7)));
      acc[cf] = __builtin_amdgcn_mfma_f32_16x16x32_bf16(a, *bp, acc[cf], 0, 0, 0);
    }
  }

  // D: col = cf*16 + lr, row = rbase + lg*4 + v
  #pragma unroll
  for (int v = 0; v < 4; ++v) {
    int row = rbase + (lg << 2) + v;
    if (row < n) {
      float s = dinv[row];
      ushort* dst = T + (size_t)row * 128 + lr;
      #pragma unroll
      for (int cf = 0; cf < 8; ++cf) dst[cf << 4] = f2bf(acc[cf][v] * s);
    }
  }
}

// ===================== sparse aggregate (bf16 in/out, fp32 accum) =====================
// Wave per node. Neighbor ids loaded with ONE coalesced per-lane read, broadcast
// via shfl; gathers issued in unroll-8 batches for MLP. No LDS -> high occupancy.
__global__ __launch_bounds__(256) void k_agg(
    const ushort* __restrict__ T, const int* __restrict__ offs,
    const int* __restrict__ csr, const float* __restrict__ dinv,
    const float* __restrict__ bias, ushort* __restrict__ H, int n, int relu)
{
  int u = (blockIdx.x << 2) + (threadIdx.x >> 6);
  if (u >= n) return;
  int lane = threadIdx.x & 63;
  const uint* Tu = (const uint*)T;
  uint su = Tu[(size_t)u * 64 + lane];   // self loop (row already * dinv[u])
  float ax = bf_lo(su), ay = bf_hi(su);
  int e0 = offs[u], e1 = offs[u + 1];
  int deg = e1 - e0;
  int dcap = deg > 64 ? 64 : deg;
  int eid = (lane < deg) ? csr[e0 + lane] : 0;   // coalesced id load
  int j = 0;
  for (; j + 8 <= dcap; j += 8) {
    int s0 = __shfl(eid, j);     int s1 = __shfl(eid, j + 1);
    int s2 = __shfl(eid, j + 2); int s3 = __shfl(eid, j + 3);
    int s4 = __shfl(eid, j + 4); int s5 = __shfl(eid, j + 5);
    int s6 = __shfl(eid, j + 6); int s7 = __shfl(eid, j + 7);
    uint v0 = Tu[(size_t)s0 * 64 + lane];
    uint v1 = Tu[(size_t)s1 * 64 + lane];
    uint v2 = Tu[(size_t)s2 * 64 + lane];
    uint v3 = Tu[(size_t)s3 * 64 + lane];
    uint v4 = Tu[(size_t)s4 * 64 + lane];
    uint v5 = Tu[(size_t)s5 * 64 + lane];
    uint v6 = Tu[(size_t)s6 * 64 + lane];
    uint v7 = Tu[(size_t)s7 * 64 + lane];
    ax += ((bf_lo(v0) + bf_lo(v1)) + (bf_lo(v2) + bf_lo(v3))) +
          ((bf_lo(v4) + bf_lo(v5)) + (bf_lo(v6) + bf_lo(v7)));
    ay += ((bf_hi(v0) + bf_hi(v1)) + (bf_hi(v2) + bf_hi(v3))) +
          ((bf_hi(v4) + bf_hi(v5)) + (bf_hi(v6) + bf_hi(v7)));
  }
  for (; j < dcap; ++j) {
    int s = __shfl(eid, j);
    uint v = Tu[(size_t)s * 64 + lane];
    ax += bf_lo(v); ay += bf_hi(v);
  }
  for (int e = e0 + 64; e < e1; ++e) {   // rare deg>64 tail
    uint v = Tu[(size_t)csr[e] * 64 + lane];
    ax += bf_lo(v); ay += bf_hi(v);
  }
  float du = dinv[u];
  float2 b2 = *(const float2*)(bias + (lane << 1));
  float ox = fmaf(ax, du, b2.x);
  float oy = fmaf(ay, du, b2.y);
  if (relu) { ox = fmaxf(ox, 0.f); oy = fmaxf(oy, 0.f); }
  ((uint*)H)[(size_t)u * 64 + lane] = pack2(ox, oy);
}

// ===================== head: logits + fused log_softmax (bf16 H) =====================
__global__ __launch_bounds__(256) void k_head(
    const ushort* __restrict__ H, const float* __restrict__ Wo,
    const float* __restrict__ bo, float* __restrict__ out, int n)
{
  __shared__ float sWo[128 * 40];   // 20 KB
  __shared__ float sX[128 * 64];    // 32 KB, swizzled transpose
  int tid = threadIdx.x;
  int rbase = blockIdx.x * 64;

  {
    const float4* Wo4 = (const float4*)Wo;
    float4* sWo4 = (float4*)sWo;
    #pragma unroll
    for (int i = 0; i < 5; ++i) sWo4[i * 256 + tid] = Wo4[i * 256 + tid];
  }
  {
    const uint4* H4 = (const uint4*)H;
    #pragma unroll
    for (int j = 0; j < 4; ++j) {
      int id = j * 256 + tid;
      int r = id & 63, kc8 = id >> 6;   // kc8 = 0..15, 8 k-elems each
      int row = rbase + r;
      uint4 v = make_uint4(0u, 0u, 0u, 0u);
      if (row < n) v = H4[(size_t)row * 16 + kc8];
      float f[8] = {bf_lo(v.x), bf_hi(v.x), bf_lo(v.y), bf_hi(v.y),
                    bf_lo(v.z), bf_hi(v.z), bf_lo(v.w), bf_hi(v.w)};
      #pragma unroll
      for (int j2 = 0; j2 < 8; ++j2) {
        int k = kc8 * 8 + j2;
        int swz = ((k >> 2) & 7) << 2;
        sX[k * 64 + (r ^ swz)] = f[j2];
      }
    }
  }
  __syncthreads();

  int cg = tid & 7;    // 8 col groups x 5 cols
  int rg = tid >> 3;   // 32 row groups x 2 rows
  float bj[5];
  #pragma unroll
  for (int j = 0; j < 5; ++j) bj[j] = bo[cg * 5 + j];
  float acc[2][5];
  #pragma unroll
  for (int i = 0; i < 2; ++i)
    #pragma unroll
    for (int j = 0; j < 5; ++j) acc[i][j] = bj[j];

  #pragma unroll 4
  for (int k = 0; k < 128; ++k) {
    int swz = ((k >> 2) & 7) << 2;
    float2 xv = *(const float2*)(sX + k * 64 + ((rg << 1) ^ swz));
    const float* wr = sWo + k * 40 + cg * 5;
    float w0 = wr[0], w1 = wr[1], w2 = wr[2], w3 = wr[3], w4 = wr[4];
    acc[0][0] = fmaf(xv.x, w0, acc[0][0]);
    acc[0][1] = fmaf(xv.x, w1, acc[0][1]);
    acc[0][2] = fmaf(xv.x, w2, acc[0][2]);
    acc[0][3] = fmaf(xv.x, w3, acc[0][3]);
    acc[0][4] = fmaf(xv.x, w4, acc[0][4]);
    acc[1][0] = fmaf(xv.y, w0, acc[1][0]);
    acc[1][1] = fmaf(xv.y, w1, acc[1][1]);
    acc[1][2] = fmaf(xv.y, w2, acc[1][2]);
    acc[1][3] = fmaf(xv.y, w3, acc[1][3]);
    acc[1][4] = fmaf(xv.y, w4, acc[1][4]);
  }

  #pragma unroll
  for (int i = 0; i < 2; ++i) {
    int row = rbase + (rg << 1) + i;
    float m = acc[i][0];
    m = fmaxf(m, acc[i][1]); m = fmaxf(m, acc[i][2]);
    m = fmaxf(m, acc[i][3]); m = fmaxf(m, acc[i][4]);
    m = fmaxf(m, __shfl_xor(m, 1));
    m = fmaxf(m, __shfl_xor(m, 2));
    m = fmaxf(m, __shfl_xor(m, 4));
    float s = 0.f;
    #pragma unroll
    for (int j = 0; j < 5; ++j) s += __expf(acc[i][j] - m);
    s += __shfl_xor(s, 1);
    s += __shfl_xor(s, 2);
    s += __shfl_xor(s, 4);
    float ls = m + __logf(s);
    if (row < n) {
      float* dst = out + (size_t)row * 40 + cg * 5;
      #pragma unroll
      for (int j = 0; j < 5; ++j) dst[j] = acc[i][j] - ls;
    }
  }
}

// ===================== launch =====================
extern "C" void kernel_launch(void* const* d_in, const int* in_sizes, int n_in,
                              void* d_out, int out_size, void* d_ws, size_t ws_size,
                              hipStream_t stream) {
  const float* x    = (const float*)d_in[0];
  const int*   edges= (const int*)d_in[1];
  const float* W_in = (const float*)d_in[2];
  const float* b_in = (const float*)d_in[3];
  const float* W1   = (const float*)d_in[4];
  const float* b1   = (const float*)d_in[5];
  const float* W2   = (const float*)d_in[6];
  const float* b2   = (const float*)d_in[7];
  const float* Wo   = (const float*)d_in[8];
  const float* bo   = (const float*)d_in[9];
  float* out = (float*)d_out;

  int N = in_sizes[0] / 128;
  int E = in_sizes[1] / 2;
  int NB = (N + 255) / 256;

  char* p = (char*)d_ws;
  auto alloc = [&](size_t bytes) {
    char* r = p; p += (bytes + 255) & ~(size_t)255; return r;
  };
  ushort* t   = (ushort*)alloc((size_t)N * 128 * 2);
  ushort* h   = (ushort*)alloc((size_t)N * 128 * 2);
  ushort* wt  = (ushort*)alloc(3 * 16384 * 2);
  int*   cnt8 = (int*)  alloc((size_t)N * 8 * 4);
  int*   cnt  = (int*)  alloc((size_t)N * 4);
  float* dinv = (float*)alloc((size_t)N * 4);
  int*   incl = (int*)  alloc((size_t)NB * 256 * 4);
  int*   bsum = (int*)  alloc(256 * 4);
  int*   offs = (int*)  alloc((size_t)(N + 1) * 4);
  int*   curs = (int*)  alloc((size_t)N * 4);
  int*   csr  = (int*)  alloc((size_t)E * 4);
  (void)ws_size; (void)n_in; (void)out_size;

  // --- prep + CSR build ---
  int NPP = (N + 7) / 8;       // nodes per partition (fill)
  int NBP = 512;               // blocks per partition (fill)
  k_prepw<<<24, 256, 0, stream>>>(W_in, W1, W2, wt);
  hipMemsetAsync(cnt8, 0, (size_t)N * 8 * 4, stream);
  k_count8<<<2048, 256, 0, stream>>>(edges, cnt8, E, N);
  k_cntred<<<NB, 256, 0, stream>>>(cnt8, cnt, dinv, N);
  k_scan1<<<NB, 256, 0, stream>>>(cnt, incl, bsum, N);
  k_scan2<<<1, 256, 0, stream>>>(bsum, NB);
  k_scan3<<<NB, 256, 0, stream>>>(incl, cnt, bsum, offs, curs, N, E);
  k_fill <<<NBP * 8, 256, 0, stream>>>(edges, curs, csr, E, NPP, NBP);

  int GB = (N + 63) / 64;
  int AB = (N + 3) / 4;

  // conv1: h1 = agg(x @ W_in) + b_in
  k_gemm<true> <<<GB, 256, 0, stream>>>(x, wt,             dinv, t, N);
  k_agg        <<<AB, 256, 0, stream>>>(t, offs, csr, dinv, b_in, h, N, 0);
  // conv2: h2 = relu(agg(h1 @ W1) + b1)
  k_gemm<false><<<GB, 256, 0, stream>>>(h, wt + 16384,     dinv, t, N);
  k_agg        <<<AB, 256, 0, stream>>>(t, offs, csr, dinv, b1, h, N, 1);
  // conv3: h3 = relu(agg(h2 @ W2) + b2)
  k_gemm<false><<<GB, 256, 0, stream>>>(h, wt + 2 * 16384, dinv, t, N);
  k_agg        <<<AB, 256, 0, stream>>>(t, offs, csr, dinv, b2, h, N, 1);

  // head + log_softmax (fused)
  k_head<<<GB, 256, 0, stream>>>(h, Wo, bo, out, N);
}

// Round 8
// 235.097 us; speedup vs baseline: 1.7398x; 1.0410x over previous
//
#include <hip/hip_runtime.h>
#include <hip/hip_bf16.h>
#include <math.h>

typedef unsigned int uint;
typedef unsigned short ushort;
typedef __attribute__((ext_vector_type(8))) short short8;   // 8 bf16 = 4 VGPRs
typedef __attribute__((ext_vector_type(4))) float f32x4;    // MFMA accumulator

__device__ __forceinline__ float bf_lo(uint u) { return __uint_as_float(u << 16); }
__device__ __forceinline__ float bf_hi(uint u) { return __uint_as_float(u & 0xffff0000u); }
__device__ __forceinline__ ushort f2bf(float f) {
  __hip_bfloat16 h = __float2bfloat16(f);   // RNE
  return *reinterpret_cast<ushort*>(&h);
}
__device__ __forceinline__ uint pack2(float a, float b) {
  return (uint)f2bf(a) | ((uint)f2bf(b) << 16);
}

// ============ fused: W prep (blocks 0..23) + replicated degree count ============
// count: single edge pass; 8 replicated count arrays, replica = (b-24)&7
// (round-robins onto XCDs) -> atomics stay XCD-local, edges read once.
__global__ __launch_bounds__(256) void k_pcnt(
    const float* __restrict__ W_in, const float* __restrict__ W1,
    const float* __restrict__ W2, ushort* __restrict__ Wt,
    const int* __restrict__ edges, int* __restrict__ cnt8, int E, int n)
{
  int b = blockIdx.x;
  if (b < 24) {
    const float* W = (b < 8) ? W_in : (b < 16) ? W1 : W2;
    ushort* dst = Wt + (size_t)(b >> 3) * 16384;
    int id = (b & 7) * 256 + threadIdx.x;    // 0..2047
    int col = id >> 4, kc = id & 15;
    const float* src = W + (size_t)(kc * 8) * 128 + col;
    uint4 pk;
    pk.x = pack2(src[0],       src[128]);
    pk.y = pack2(src[2 * 128], src[3 * 128]);
    pk.z = pack2(src[4 * 128], src[5 * 128]);
    pk.w = pack2(src[6 * 128], src[7 * 128]);
    ((uint4*)dst)[id] = pk;
  } else {
    int cb = b - 24;
    int* my = cnt8 + (size_t)(cb & 7) * n;
    int stride = ((int)gridDim.x - 24) * 256;
    for (int e = cb * 256 + threadIdx.x; e < E; e += stride)
      atomicAdd(&my[edges[E + e]], 1);
  }
}

// ============ scan1: fused replica-reduce + dinv + block-inclusive scan ============
__global__ void k_scan1(const int* __restrict__ cnt8, int* __restrict__ cnt,
                        int* __restrict__ incl, int* __restrict__ bsum,
                        float* __restrict__ dinv, int n) {
  __shared__ int s[256];
  int tid = threadIdx.x;
  int gid = blockIdx.x * 256 + tid;
  int x = 0;
  if (gid < n) {
    #pragma unroll
    for (int p = 0; p < 8; ++p) x += cnt8[(size_t)p * n + gid];
    cnt[gid] = x;
    dinv[gid] = rsqrtf((float)x + 1.0f);   // +1 = self loop
  }
  s[tid] = x;
  __syncthreads();
  #pragma unroll
  for (int off = 1; off < 256; off <<= 1) {
    int t = (tid >= off) ? s[tid - off] : 0;
    __syncthreads();
    x += t; s[tid] = x;
    __syncthreads();
  }
  incl[gid] = x;
  if (tid == 255) bsum[blockIdx.x] = x;
}

// ============ scan3: each block reduces bsum[0..bid) itself (nb <= 256) ============
__global__ void k_scan3(const int* __restrict__ incl, const int* __restrict__ cnt,
                        const int* __restrict__ bsum, int* __restrict__ offs,
                        int* __restrict__ curs, int n, int E, int nb) {
  __shared__ int sb[256];
  int tid = threadIdx.x;
  sb[tid] = (tid < (int)blockIdx.x && tid < nb) ? bsum[tid] : 0;
  __syncthreads();
  #pragma unroll
  for (int off = 128; off; off >>= 1) {
    if (tid < off) sb[tid] += sb[tid + off];
    __syncthreads();
  }
  int base = sb[0];
  int gid = blockIdx.x * 256 + tid;
  if (gid < n) {
    int v = incl[gid] - cnt[gid] + base;   // exclusive
    offs[gid] = v;
    curs[gid] = v;
  }
  if (gid == 0) offs[n] = E;
}

// ============ fat kernel: gemm1 (blocks < gb) || CSR fill (blocks >= gb) ============
// gemm: wave = 16 rows x 128 cols via 8x mfma_f32_16x16x32_bf16; W in LDS
// (kc^(col&7) swizzle); A fp32 global->VGPR with inline bf16 convert.
// fill: XCD-partitioned by dst range (part = b&7) -> curs atomics + csr lines L2-local.
__global__ __launch_bounds__(256) void k_gf(
    const float* __restrict__ A, const ushort* __restrict__ Wt,
    const float* __restrict__ dinv, ushort* __restrict__ T, int n, int gb,
    const int* __restrict__ edges, int* __restrict__ curs,
    int* __restrict__ csr, int E, int npp, int nbp)
{
  __shared__ ushort sW[128 * 128];
  int tid = threadIdx.x;

  if ((int)blockIdx.x >= gb) {   // ---- fill path ----
    int b2 = blockIdx.x - gb;
    int part = b2 & 7;
    int lo = part * npp, hi = lo + npp;
    for (int e = (b2 >> 3) * 256 + tid; e < E; e += nbp * 256) {
      int d = edges[E + e];
      if (d >= lo && d < hi) {
        int s = edges[e];
        int pos = atomicAdd(&curs[d], 1);
        csr[pos] = s;
      }
    }
    return;
  }

  // ---- gemm path ----
  {
    const uint4* Wt4 = (const uint4*)Wt;
    uint4* sW4 = (uint4*)sW;
    #pragma unroll
    for (int j = 0; j < 8; ++j) {
      int id = j * 256 + tid;
      int col = id >> 4, kc = id & 15;
      sW4[(col << 4) | (kc ^ (col & 7))] = Wt4[id];
    }
  }
  __syncthreads();

  int wid = tid >> 6, lane = tid & 63;
  int lr = lane & 15, lg = lane >> 4;
  int rbase = blockIdx.x * 64 + wid * 16;
  int arow = rbase + lr;
  bool valid = arow < n;

  f32x4 acc[8];
  #pragma unroll
  for (int cf = 0; cf < 8; ++cf) acc[cf] = (f32x4){0.f, 0.f, 0.f, 0.f};

  #pragma unroll
  for (int ks = 0; ks < 4; ++ks) {
    short8 a = {};
    if (valid) {
      const float4* Af = (const float4*)(A + (size_t)arow * 128) + (ks * 4 + lg) * 2;
      float4 u = Af[0], w = Af[1];
      union { uint4 u4; short8 s8; } cv;
      cv.u4.x = pack2(u.x, u.y); cv.u4.y = pack2(u.z, u.w);
      cv.u4.z = pack2(w.x, w.y); cv.u4.w = pack2(w.z, w.w);
      a = cv.s8;
    }
    int kc = (ks << 2) | lg;
    #pragma unroll
    for (int cf = 0; cf < 8; ++cf) {
      int col = (cf << 4) | lr;
      const short8* bp = (const short8*)sW + ((col << 4) | (kc ^ (lr & 7)));
      acc[cf] = __builtin_amdgcn_mfma_f32_16x16x32_bf16(a, *bp, acc[cf], 0, 0, 0);
    }
  }

  #pragma unroll
  for (int v = 0; v < 4; ++v) {
    int row = rbase + (lg << 2) + v;
    if (row < n) {
      float s = dinv[row];
      ushort* dst = T + (size_t)row * 128 + lr;
      #pragma unroll
      for (int cf = 0; cf < 8; ++cf) dst[cf << 4] = f2bf(acc[cf][v] * s);
    }
  }
}

// ===================== MFMA GEMM (bf16 A), layers 2-3 =====================
__global__ __launch_bounds__(256) void k_gemm(
    const ushort* __restrict__ Ap, const ushort* __restrict__ Wt,
    const float* __restrict__ dinv, ushort* __restrict__ T, int n)
{
  __shared__ ushort sW[128 * 128];
  int tid = threadIdx.x;
  {
    const uint4* Wt4 = (const uint4*)Wt;
    uint4* sW4 = (uint4*)sW;
    #pragma unroll
    for (int j = 0; j < 8; ++j) {
      int id = j * 256 + tid;
      int col = id >> 4, kc = id & 15;
      sW4[(col << 4) | (kc ^ (col & 7))] = Wt4[id];
    }
  }
  __syncthreads();

  int wid = tid >> 6, lane = tid & 63;
  int lr = lane & 15, lg = lane >> 4;
  int rbase = blockIdx.x * 64 + wid * 16;
  int arow = rbase + lr;
  bool valid = arow < n;

  f32x4 acc[8];
  #pragma unroll
  for (int cf = 0; cf < 8; ++cf) acc[cf] = (f32x4){0.f, 0.f, 0.f, 0.f};

  #pragma unroll
  for (int ks = 0; ks < 4; ++ks) {
    short8 a = {};
    if (valid) a = ((const short8*)(Ap + (size_t)arow * 128))[ks * 4 + lg];
    int kc = (ks << 2) | lg;
    #pragma unroll
    for (int cf = 0; cf < 8; ++cf) {
      int col = (cf << 4) | lr;
      const short8* bp = (const short8*)sW + ((col << 4) | (kc ^ (lr & 7)));
      acc[cf] = __builtin_amdgcn_mfma_f32_16x16x32_bf16(a, *bp, acc[cf], 0, 0, 0);
    }
  }

  #pragma unroll
  for (int v = 0; v < 4; ++v) {
    int row = rbase + (lg << 2) + v;
    if (row < n) {
      float s = dinv[row];
      ushort* dst = T + (size_t)row * 128 + lr;
      #pragma unroll
      for (int cf = 0; cf < 8; ++cf) dst[cf << 4] = f2bf(acc[cf][v] * s);
    }
  }
}

// ===================== sparse aggregate (bf16 in/out, fp32 accum) =====================
// Wave per node; coalesced neighbor-id load + shfl broadcast; unroll-8 gathers.
__global__ __launch_bounds__(256) void k_agg(
    const ushort* __restrict__ T, const int* __restrict__ offs,
    const int* __restrict__ csr, const float* __restrict__ dinv,
    const float* __restrict__ bias, ushort* __restrict__ H, int n, int relu)
{
  int u = (blockIdx.x << 2) + (threadIdx.x >> 6);
  if (u >= n) return;
  int lane = threadIdx.x & 63;
  const uint* Tu = (const uint*)T;
  uint su = Tu[(size_t)u * 64 + lane];   // self loop (row already * dinv[u])
  float ax = bf_lo(su), ay = bf_hi(su);
  int e0 = offs[u], e1 = offs[u + 1];
  int deg = e1 - e0;
  int dcap = deg > 64 ? 64 : deg;
  int eid = (lane < deg) ? csr[e0 + lane] : 0;   // coalesced id load
  int j = 0;
  for (; j + 8 <= dcap; j += 8) {
    int s0 = __shfl(eid, j);     int s1 = __shfl(eid, j + 1);
    int s2 = __shfl(eid, j + 2); int s3 = __shfl(eid, j + 3);
    int s4 = __shfl(eid, j + 4); int s5 = __shfl(eid, j + 5);
    int s6 = __shfl(eid, j + 6); int s7 = __shfl(eid, j + 7);
    uint v0 = Tu[(size_t)s0 * 64 + lane];
    uint v1 = Tu[(size_t)s1 * 64 + lane];
    uint v2 = Tu[(size_t)s2 * 64 + lane];
    uint v3 = Tu[(size_t)s3 * 64 + lane];
    uint v4 = Tu[(size_t)s4 * 64 + lane];
    uint v5 = Tu[(size_t)s5 * 64 + lane];
    uint v6 = Tu[(size_t)s6 * 64 + lane];
    uint v7 = Tu[(size_t)s7 * 64 + lane];
    ax += ((bf_lo(v0) + bf_lo(v1)) + (bf_lo(v2) + bf_lo(v3))) +
          ((bf_lo(v4) + bf_lo(v5)) + (bf_lo(v6) + bf_lo(v7)));
    ay += ((bf_hi(v0) + bf_hi(v1)) + (bf_hi(v2) + bf_hi(v3))) +
          ((bf_hi(v4) + bf_hi(v5)) + (bf_hi(v6) + bf_hi(v7)));
  }
  for (; j < dcap; ++j) {
    int s = __shfl(eid, j);
    uint v = Tu[(size_t)s * 64 + lane];
    ax += bf_lo(v); ay += bf_hi(v);
  }
  for (int e = e0 + 64; e < e1; ++e) {   // rare deg>64 tail
    uint v = Tu[(size_t)csr[e] * 64 + lane];
    ax += bf_lo(v); ay += bf_hi(v);
  }
  float du = dinv[u];
  float2 b2 = *(const float2*)(bias + (lane << 1));
  float ox = fmaf(ax, du, b2.x);
  float oy = fmaf(ay, du, b2.y);
  if (relu) { ox = fmaxf(ox, 0.f); oy = fmaxf(oy, 0.f); }
  ((uint*)H)[(size_t)u * 64 + lane] = pack2(ox, oy);
}

// ===================== head: logits + fused log_softmax (bf16 H) =====================
__global__ __launch_bounds__(256) void k_head(
    const ushort* __restrict__ H, const float* __restrict__ Wo,
    const float* __restrict__ bo, float* __restrict__ out, int n)
{
  __shared__ float sWo[128 * 40];   // 20 KB
  __shared__ float sX[128 * 64];    // 32 KB, swizzled transpose
  int tid = threadIdx.x;
  int rbase = blockIdx.x * 64;

  {
    const float4* Wo4 = (const float4*)Wo;
    float4* sWo4 = (float4*)sWo;
    #pragma unroll
    for (int i = 0; i < 5; ++i) sWo4[i * 256 + tid] = Wo4[i * 256 + tid];
  }
  {
    const uint4* H4 = (const uint4*)H;
    #pragma unroll
    for (int j = 0; j < 4; ++j) {
      int id = j * 256 + tid;
      int r = id & 63, kc8 = id >> 6;   // kc8 = 0..15, 8 k-elems each
      int row = rbase + r;
      uint4 v = make_uint4(0u, 0u, 0u, 0u);
      if (row < n) v = H4[(size_t)row * 16 + kc8];
      float f[8] = {bf_lo(v.x), bf_hi(v.x), bf_lo(v.y), bf_hi(v.y),
                    bf_lo(v.z), bf_hi(v.z), bf_lo(v.w), bf_hi(v.w)};
      #pragma unroll
      for (int j2 = 0; j2 < 8; ++j2) {
        int k = kc8 * 8 + j2;
        int swz = ((k >> 2) & 7) << 2;
        sX[k * 64 + (r ^ swz)] = f[j2];
      }
    }
  }
  __syncthreads();

  int cg = tid & 7;    // 8 col groups x 5 cols
  int rg = tid >> 3;   // 32 row groups x 2 rows
  float bj[5];
  #pragma unroll
  for (int j = 0; j < 5; ++j) bj[j] = bo[cg * 5 + j];
  float acc[2][5];
  #pragma unroll
  for (int i = 0; i < 2; ++i)
    #pragma unroll
    for (int j = 0; j < 5; ++j) acc[i][j] = bj[j];

  #pragma unroll 4
  for (int k = 0; k < 128; ++k) {
    int swz = ((k >> 2) & 7) << 2;
    float2 xv = *(const float2*)(sX + k * 64 + ((rg << 1) ^ swz));
    const float* wr = sWo + k * 40 + cg * 5;
    float w0 = wr[0], w1 = wr[1], w2 = wr[2], w3 = wr[3], w4 = wr[4];
    acc[0][0] = fmaf(xv.x, w0, acc[0][0]);
    acc[0][1] = fmaf(xv.x, w1, acc[0][1]);
    acc[0][2] = fmaf(xv.x, w2, acc[0][2]);
    acc[0][3] = fmaf(xv.x, w3, acc[0][3]);
    acc[0][4] = fmaf(xv.x, w4, acc[0][4]);
    acc[1][0] = fmaf(xv.y, w0, acc[1][0]);
    acc[1][1] = fmaf(xv.y, w1, acc[1][1]);
    acc[1][2] = fmaf(xv.y, w2, acc[1][2]);
    acc[1][3] = fmaf(xv.y, w3, acc[1][3]);
    acc[1][4] = fmaf(xv.y, w4, acc[1][4]);
  }

  #pragma unroll
  for (int i = 0; i < 2; ++i) {
    int row = rbase + (rg << 1) + i;
    float m = acc[i][0];
    m = fmaxf(m, acc[i][1]); m = fmaxf(m, acc[i][2]);
    m = fmaxf(m, acc[i][3]); m = fmaxf(m, acc[i][4]);
    m = fmaxf(m, __shfl_xor(m, 1));
    m = fmaxf(m, __shfl_xor(m, 2));
    m = fmaxf(m, __shfl_xor(m, 4));
    float s = 0.f;
    #pragma unroll
    for (int j = 0; j < 5; ++j) s += __expf(acc[i][j] - m);
    s += __shfl_xor(s, 1);
    s += __shfl_xor(s, 2);
    s += __shfl_xor(s, 4);
    float ls = m + __logf(s);
    if (row < n) {
      float* dst = out + (size_t)row * 40 + cg * 5;
      #pragma unroll
      for (int j = 0; j < 5; ++j) dst[j] = acc[i][j] - ls;
    }
  }
}

// ===================== launch =====================
extern "C" void kernel_launch(void* const* d_in, const int* in_sizes, int n_in,
                              void* d_out, int out_size, void* d_ws, size_t ws_size,
                              hipStream_t stream) {
  const float* x    = (const float*)d_in[0];
  const int*   edges= (const int*)d_in[1];
  const float* W_in = (const float*)d_in[2];
  const float* b_in = (const float*)d_in[3];
  const float* W1   = (const float*)d_in[4];
  const float* b1   = (const float*)d_in[5];
  const float* W2   = (const float*)d_in[6];
  const float* b2   = (const float*)d_in[7];
  const float* Wo   = (const float*)d_in[8];
  const float* bo   = (const float*)d_in[9];
  float* out = (float*)d_out;

  int N = in_sizes[0] / 128;
  int E = in_sizes[1] / 2;
  int NB = (N + 255) / 256;

  char* p = (char*)d_ws;
  auto alloc = [&](size_t bytes) {
    char* r = p; p += (bytes + 255) & ~(size_t)255; return r;
  };
  ushort* t   = (ushort*)alloc((size_t)N * 128 * 2);
  ushort* h   = (ushort*)alloc((size_t)N * 128 * 2);
  ushort* wt  = (ushort*)alloc(3 * 16384 * 2);
  int*   cnt8 = (int*)  alloc((size_t)N * 8 * 4);
  int*   cnt  = (int*)  alloc((size_t)N * 4);
  float* dinv = (float*)alloc((size_t)N * 4);
  int*   incl = (int*)  alloc((size_t)NB * 256 * 4);
  int*   bsum = (int*)  alloc(256 * 4);
  int*   offs = (int*)  alloc((size_t)(N + 1) * 4);
  int*   curs = (int*)  alloc((size_t)N * 4);
  int*   csr  = (int*)  alloc((size_t)E * 4);
  (void)ws_size; (void)n_in; (void)out_size;

  int NPP = (N + 7) / 8;       // nodes per partition (fill)
  int NBP = 512;               // blocks per partition (fill)
  int GB = (N + 63) / 64;
  int AB = (N + 3) / 4;

  // --- CSR build + W prep (fused / overlapped) ---
  hipMemsetAsync(cnt8, 0, (size_t)N * 8 * 4, stream);
  k_pcnt <<<24 + 2048, 256, 0, stream>>>(W_in, W1, W2, wt, edges, cnt8, E, N);
  k_scan1<<<NB, 256, 0, stream>>>(cnt8, cnt, incl, bsum, dinv, N);
  k_scan3<<<NB, 256, 0, stream>>>(incl, cnt, bsum, offs, curs, N, E, NB);
  // gemm1 (x fp32 @ W_in) overlapped with CSR fill
  k_gf   <<<GB + NBP * 8, 256, 0, stream>>>(x, wt, dinv, t, N, GB,
                                            edges, curs, csr, E, NPP, NBP);
  k_agg  <<<AB, 256, 0, stream>>>(t, offs, csr, dinv, b_in, h, N, 0);
  // conv2
  k_gemm <<<GB, 256, 0, stream>>>(h, wt + 16384, dinv, t, N);
  k_agg  <<<AB, 256, 0, stream>>>(t, offs, csr, dinv, b1, h, N, 1);
  // conv3
  k_gemm <<<GB, 256, 0, stream>>>(h, wt + 2 * 16384, dinv, t, N);
  k_agg  <<<AB, 256, 0, stream>>>(t, offs, csr, dinv, b2, h, N, 1);

  // head + log_softmax (fused)
  k_head <<<GB, 256, 0, stream>>>(h, Wo, bo, out, N);
}